// Round 6
// baseline (875.217 us; speedup 1.0000x reference)
//
#include <hip/hip_runtime.h>
#include <float.h>

// VectorQuantize: h=8 heads, c=2048 codes, d=64, b=8, t=2048 (n=16384 vec/head)
#define H   8
#define C   2048
#define D   64
#define NPH 16384     // vectors per head (b*t)
#define HD  512       // h*d
#define DECAYF 0.9f
#define CT  256       // code tile
#define NT  (C/CT)    // 8 code tiles

// ---------------------------------------------------------------------------
// Kernel 0: e_sq[h,c] = sum_d ke[h,c,d]^2
// ---------------------------------------------------------------------------
__global__ __launch_bounds__(256) void vq_esq_kernel(const float* __restrict__ ke,
                                                     float* __restrict__ esq) {
    int i = blockIdx.x * 256 + threadIdx.x;   // 0 .. H*C-1
    const float* e = ke + (size_t)i * D;
    float s = 0.f;
#pragma unroll
    for (int d = 0; d < D; ++d) s = fmaf(e[d], e[d], s);
    esq[i] = s;
}

// ---------------------------------------------------------------------------
// Kernel 1: register-tiled distance GEMM + argmin, 8x16 acc + reg prefetch.
//   R6 change vs R5: amdgpu_waves_per_eu(2,2) pins the allocator to a
//   256-VGPR budget. R5's allocator targeted 128 VGPRs (occupancy heuristic)
//   while acc[8][16] alone is 128 -> everything else spilled (+28.6MB scratch
//   writes). LDS caps us at 2 blocks/CU regardless, so max=2 is free.
//   Tile geometry rationale: 8x16 acc = 96 B LDS per 128 FMA; at ~85 B/cyc/CU
//   ds_read_b128 throughput that supports ~113 FMA/cyc vs 128 VALU peak
//   (8x8 tile = 128 B / 64 FMA = 33% cap, matching R3/R4's 33% VALUBusy).
//   Distance math bit-identical to all passing rounds (fmaf k ascending,
//   (xsq-2dot)+esq, first-min ascending-index tie-break).
// ---------------------------------------------------------------------------
// smem float offsets:
//   sx   [    0,  8192)  x^T tile [k][v] 64x128  (alive until scatter)
//   se   [ 8192, 16384)  e^T chunk [kk][c] 32x256 (aliased by rb/ri at end)
//   sesq [16384, 16640)  e_sq for current code tile (256)
//   sxsq [16640, 16768)  x_sq per vector (128)
//   sidx [16768, 16896)  chosen code per vector (int, 128)
//   rb = smem+8192 [16][128], ri = (int*)(smem+10240) [16][128]
#define SMEM_FLOATS 16896

__global__ __launch_bounds__(256)
__attribute__((amdgpu_waves_per_eu(2, 2)))
void vq_main_kernel(const float* __restrict__ x,
                    const float* __restrict__ ke,
                    const float* __restrict__ esq,
                    float* __restrict__ outq,
                    float* __restrict__ outi,
                    float* __restrict__ embsum) {
    __shared__ __align__(16) float smem[SMEM_FLOATS];
    float* sx   = smem;
    float* se   = smem + 8192;
    float* sesq = smem + 16384;
    float* sxsq = smem + 16640;
    int*   sidx = (int*)(smem + 16768);

    const int tid = threadIdx.x;
    const int tx  = tid & 15;    // code group (4 codes in each of 4 strips)
    const int ty  = tid >> 4;    // vec group (8 vecs)
    const int h   = blockIdx.x & 7;
    const int vt  = blockIdx.x >> 3;
    const int n0  = vt * 128;    // first vector of this block (within head)

    const float* keh  = ke  + (size_t)h * C * D;
    const float* esqh = esq + (size_t)h * C;

    // ---- stage x^T: sx[k][v] = x[n0+v][h*64+k] ----
    {
        const int v  = tid >> 1;
        const int kb = (tid & 1) * 32;
        const float* xp = x + (size_t)(n0 + v) * HD + (size_t)h * D + kb;
#pragma unroll
        for (int i = 0; i < 8; ++i) {
            float4 w = ((const float4*)xp)[i];
            sx[(kb + 4 * i + 0) * 128 + v] = w.x;
            sx[(kb + 4 * i + 1) * 128 + v] = w.y;
            sx[(kb + 4 * i + 2) * 128 + v] = w.z;
            sx[(kb + 4 * i + 3) * 128 + v] = w.w;
        }
    }

    // ---- prefetch first se chunk (tile 0, k 0..31) + first esq tile ----
    // thread tid loads code (cb + tid), 8 float4 = k range of the chunk
    float4 pf[8];
    {
        const float* ep = keh + (size_t)tid * D;   // tile 0, kc 0
#pragma unroll
        for (int i = 0; i < 8; ++i) pf[i] = ((const float4*)ep)[i];
    }
    float pesq = esqh[tid];                        // tile 0 e_sq

    __syncthreads();

    // ---- xsq per vector (sequential fmaf over k: matches reference order) ----
    if (tid < 128) {
        float s = 0.f;
        for (int k = 0; k < 64; ++k) {
            float v = sx[k * 128 + tid];
            s = fmaf(v, v, s);
        }
        sxsq[tid] = s;
    }
    __syncthreads();

    float xq[8];
#pragma unroll
    for (int r = 0; r < 8; ++r) xq[r] = sxsq[ty * 8 + r];

    float best[8];
    int   bidx[8];
#pragma unroll
    for (int r = 0; r < 8; ++r) { best[r] = FLT_MAX; bidx[r] = 0x7fffffff; }

    // ---- loop over 8 code tiles x 2 k-chunks ----
    for (int t = 0; t < NT; ++t) {
        const int cb = t * CT;

        float acc[8][16];
#pragma unroll
        for (int r = 0; r < 8; ++r)
#pragma unroll
            for (int j = 0; j < 16; ++j) acc[r][j] = 0.f;

        for (int kc = 0; kc < 2; ++kc) {
            __syncthreads();   // previous chunk's readers done before overwrite

            // write prefetched chunk: se[kk][c] = ke[h][cb+c][kc*32+kk]
#pragma unroll
            for (int i = 0; i < 8; ++i) {
                se[(4 * i + 0) * 256 + tid] = pf[i].x;
                se[(4 * i + 1) * 256 + tid] = pf[i].y;
                se[(4 * i + 2) * 256 + tid] = pf[i].z;
                se[(4 * i + 3) * 256 + tid] = pf[i].w;
            }
            if (kc == 0) sesq[tid] = pesq;

            // issue next chunk's global loads (land during compute below)
            {
                int nt_ = t, nkc = kc + 1;
                if (nkc == 2) { nkc = 0; ++nt_; }
                if (nt_ < NT) {
                    const float* ep = keh + (size_t)(nt_ * CT + tid) * D + nkc * 32;
#pragma unroll
                    for (int i = 0; i < 8; ++i) pf[i] = ((const float4*)ep)[i];
                }
            }
            if (kc == 1 && t + 1 < NT) pesq = esqh[(t + 1) * CT + tid];

            __syncthreads();

            // 8x16 register-tile dot products over this k-chunk
            for (int kk = 0; kk < 32; ++kk) {
                const int k = kc * 32 + kk;
                float4 xa0 = *(const float4*)&sx[k * 128 + ty * 8];
                float4 xa1 = *(const float4*)&sx[k * 128 + ty * 8 + 4];
                float4 e0  = *(const float4*)&se[kk * 256 +   0 + tx * 4];
                float4 e1  = *(const float4*)&se[kk * 256 +  64 + tx * 4];
                float4 e2  = *(const float4*)&se[kk * 256 + 128 + tx * 4];
                float4 e3  = *(const float4*)&se[kk * 256 + 192 + tx * 4];
                float xa[8]  = {xa0.x, xa0.y, xa0.z, xa0.w, xa1.x, xa1.y, xa1.z, xa1.w};
                float eb[16] = {e0.x, e0.y, e0.z, e0.w, e1.x, e1.y, e1.z, e1.w,
                                e2.x, e2.y, e2.z, e2.w, e3.x, e3.y, e3.z, e3.w};
#pragma unroll
                for (int r = 0; r < 8; ++r)
#pragma unroll
                    for (int j = 0; j < 16; ++j)
                        acc[r][j] = fmaf(xa[r], eb[j], acc[r][j]);
            }
        }

        // epilogue: d2 = (xsq - 2*dot) + esq ; running first-min
        // code = cb + q*64 + tx*4 + j  (ascending in (q,j) per thread)
#pragma unroll
        for (int r = 0; r < 8; ++r) {
#pragma unroll
            for (int q = 0; q < 4; ++q)
#pragma unroll
                for (int j = 0; j < 4; ++j) {
                    const int cc = q * 64 + tx * 4 + j;
                    float d2 = (xq[r] - 2.f * acc[r][q * 4 + j]) + sesq[cc];
                    if (d2 < best[r]) { best[r] = d2; bidx[r] = cb + cc; }
                }
        }
    }

    // ---- cross-thread argmin reduction (rb/ri alias se) ----
    __syncthreads();
    float* rb = smem + 8192;
    int*   ri = (int*)(smem + 10240);
#pragma unroll
    for (int r = 0; r < 8; ++r) {
        rb[tx * 128 + ty * 8 + r] = best[r];
        ri[tx * 128 + ty * 8 + r] = bidx[r];
    }
    __syncthreads();
    if (tid < 128) {
        const int v = tid;
        float bb = FLT_MAX;
        int   bi = 0x7fffffff;
        for (int g = 0; g < 16; ++g) {
            float b = rb[g * 128 + v];
            int   i = ri[g * 128 + v];
            if (b < bb || (b == bb && i < bi)) { bb = b; bi = i; }
        }
        sidx[v] = bi;
        outi[(size_t)(n0 + v) * H + h] = (float)bi;   // [b,t,h]
    }
    __syncthreads();

    // ---- gather quantized vectors + scatter-add into emb_sum ----
    {
        const int v  = tid >> 1;
        const int db = (tid & 1) * 32;
        const int ci = sidx[v];
        const float* ev = keh + (size_t)ci * D + db;
        float* qo = outq + (size_t)(n0 + v) * HD + (size_t)h * D + db;
#pragma unroll
        for (int i = 0; i < 8; ++i)
            ((float4*)qo)[i] = ((const float4*)ev)[i];

        float* es = embsum + ((size_t)h * C + ci) * D + db;
#pragma unroll
        for (int d = 0; d < 32; ++d)
            atomicAdd(es + d, sx[(db + d) * 128 + v]);
    }
}

// ---------------------------------------------------------------------------
// Kernel 2: new_ke = key_optim ? ke + 0.9*(emb_sum - ke) : ke
// ---------------------------------------------------------------------------
__global__ __launch_bounds__(256) void vq_lerp_kernel(const float* __restrict__ ke,
                                                      const float* __restrict__ embsum,
                                                      const int* __restrict__ ko,
                                                      float* __restrict__ outk) {
    int i = (blockIdx.x * 256 + threadIdx.x) * 4;   // H*C*D = 1048576 floats
    const int on = ko[0];
    float4 k4 = *(const float4*)(ke + i);
    float4 s4 = *(const float4*)(embsum + i);
    float4 o4;
    if (on) {
        o4.x = k4.x + DECAYF * (s4.x - k4.x);
        o4.y = k4.y + DECAYF * (s4.y - k4.y);
        o4.z = k4.z + DECAYF * (s4.z - k4.z);
        o4.w = k4.w + DECAYF * (s4.w - k4.w);
    } else {
        o4 = k4;
    }
    *(float4*)(outk + i) = o4;
}

extern "C" void kernel_launch(void* const* d_in, const int* in_sizes, int n_in,
                              void* d_out, int out_size, void* d_ws, size_t ws_size,
                              hipStream_t stream) {
    const float* x  = (const float*)d_in[0];
    const float* ke = (const float*)d_in[1];
    const int*   ko = (const int*)d_in[2];

    float* out  = (float*)d_out;
    float* outq = out;                                   // 8,388,608 floats
    float* outi = out + (size_t)H * NPH * D;             // +131,072 floats
    float* outk = outi + (size_t)NPH * H;                // +1,048,576 floats

    float* embsum = (float*)d_ws;                        // H*C*D f32
    float* esq    = embsum + (size_t)H * C * D;          // 16,384 f32

    // zero the scatter accumulator every call (graph-replay safe)
    hipMemsetAsync(embsum, 0, (size_t)H * C * D * sizeof(float), stream);

    vq_esq_kernel<<<(H * C) / 256, 256, 0, stream>>>(ke, esq);
    vq_main_kernel<<<1024, 256, 0, stream>>>(x, ke, esq, outq, outi, embsum);
    vq_lerp_kernel<<<(H * C * D) / (256 * 4), 256, 0, stream>>>(ke, embsum, ko, outk);
}

// Round 7
// 824.400 us; speedup vs baseline: 1.0616x; 1.0616x over previous
//
#include <hip/hip_runtime.h>
#include <float.h>

// VectorQuantize: h=8 heads, c=2048 codes, d=64, b=8, t=2048 (n=16384 vec/head)
#define H   8
#define C   2048
#define D   64
#define NPH 16384     // vectors per head (b*t)
#define HD  512       // h*d
#define DECAYF 0.9f
#define CT  128       // code tile
#define NT  (C/CT)    // 16 code tiles

// ---------------------------------------------------------------------------
// Kernel 0: e_sq[h,c] = sum_d ke[h,c,d]^2
// ---------------------------------------------------------------------------
__global__ __launch_bounds__(256) void vq_esq_kernel(const float* __restrict__ ke,
                                                     float* __restrict__ esq) {
    int i = blockIdx.x * 256 + threadIdx.x;   // 0 .. H*C-1
    const float* e = ke + (size_t)i * D;
    float s = 0.f;
#pragma unroll
    for (int d = 0; d < D; ++d) s = fmaf(e[d], e[d], s);
    esq[i] = s;
}

// ---------------------------------------------------------------------------
// Kernel 1: register-tiled distance GEMM + argmin. R7: sized for the 128-VGPR
//   wall the allocator enforced in R5/R6 (two pinning attempts failed at
//   exactly 128 + spill). acc[8][8]=64 regs + pf[4]=16 + best/bidx 16 fits.
//   Ping-pong LDS chunk buffers (se0/se1, [32][128] each) -> ONE barrier per
//   chunk; register prefetch keeps global loads a full compute phase ahead.
//   Argmin scans score = esq[c] - 2*dot (per-row x^2 constant dropped:
//   argmin-invariant up to ulp ties; R1-R6 passed with independent fp
//   ordering and zero index flips => margins >> ulp).
//   Thread (tx,ty)=(tid&15,tid>>4): vecs ty*8..+7, codes {tx*4..+3} u
//   {64+tx*4..+3} of each 128-tile (16B lane stride -> 2-way wrap = free).
// ---------------------------------------------------------------------------
// smem float offsets:
//   sx    [    0,  8192)  x^T [k][v] 64x128   (alive until scatter)
//   se0   [ 8192, 12288)  chunk buf A [kk][c] 32x128
//   se1   [12288, 16384)  chunk buf B [kk][c] 32x128
//   sesqa [16384, 18432)  e_sq for whole head (2048)
//   sidx  [18432, 18560)  chosen code per vector (int, 128)
//   rb = smem+8192 [16][128], ri = (int*)(smem+10240) [16][128] (alias se)
#define SMEM_FLOATS 18560

__global__ __launch_bounds__(256, 2)
void vq_main_kernel(const float* __restrict__ x,
                    const float* __restrict__ ke,
                    const float* __restrict__ esq,
                    float* __restrict__ outq,
                    float* __restrict__ outi,
                    float* __restrict__ embsum) {
    __shared__ __align__(16) float smem[SMEM_FLOATS];
    float* sx    = smem;
    float* se0   = smem + 8192;
    float* se1   = smem + 12288;
    float* sesqa = smem + 16384;
    int*   sidx  = (int*)(smem + 18432);

    const int tid = threadIdx.x;
    const int tx  = tid & 15;    // code group
    const int ty  = tid >> 4;    // vec group (8 vecs)
    const int h   = blockIdx.x & 7;
    const int vt  = blockIdx.x >> 3;
    const int n0  = vt * 128;    // first vector of this block (within head)

    const float* keh  = ke  + (size_t)h * C * D;
    const float* esqh = esq + (size_t)h * C;

    // staging role: this thread stages code-row `prow`, k-range [pkb, pkb+16)
    const int prow = tid >> 1;
    const int pkb  = (tid & 1) * 16;

    float4 pf[4];
    // issue chunk(tile0, kc0) loads first so latency hides under staging
    {
        const float* ep = keh + (size_t)prow * D + pkb;
#pragma unroll
        for (int i = 0; i < 4; ++i) pf[i] = ((const float4*)ep)[i];
    }

    // ---- stage x^T: sx[k][v] = x[n0+v][h*64+k] ----
    {
        const int v  = tid >> 1;
        const int kb = (tid & 1) * 32;
        const float* xp = x + (size_t)(n0 + v) * HD + (size_t)h * D + kb;
#pragma unroll
        for (int i = 0; i < 8; ++i) {
            float4 w = ((const float4*)xp)[i];
            sx[(kb + 4 * i + 0) * 128 + v] = w.x;
            sx[(kb + 4 * i + 1) * 128 + v] = w.y;
            sx[(kb + 4 * i + 2) * 128 + v] = w.z;
            sx[(kb + 4 * i + 3) * 128 + v] = w.w;
        }
    }
    // ---- stage whole head's e_sq ----
#pragma unroll
    for (int i = 0; i < 8; ++i) sesqa[tid + 256 * i] = esqh[tid + 256 * i];

    // write chunk(0,0) -> se0 ; issue chunk(0,1) -> pf
#pragma unroll
    for (int i = 0; i < 4; ++i) {
        se0[(pkb + 4 * i + 0) * 128 + prow] = pf[i].x;
        se0[(pkb + 4 * i + 1) * 128 + prow] = pf[i].y;
        se0[(pkb + 4 * i + 2) * 128 + prow] = pf[i].z;
        se0[(pkb + 4 * i + 3) * 128 + prow] = pf[i].w;
    }
    {
        const float* ep = keh + (size_t)prow * D + 32 + pkb;
#pragma unroll
        for (int i = 0; i < 4; ++i) pf[i] = ((const float4*)ep)[i];
    }
    __syncthreads();

    float best[8];
    int   bidx[8];
#pragma unroll
    for (int r = 0; r < 8; ++r) { best[r] = FLT_MAX; bidx[r] = 0x7fffffff; }

#pragma unroll 1
    for (int t = 0; t < NT; ++t) {
        const int tn = (t + 1) & (NT - 1);   // wrapped next tile (tail work harmless)

        float acc[8][8];
#pragma unroll
        for (int r = 0; r < 8; ++r)
#pragma unroll
            for (int j = 0; j < 8; ++j) acc[r][j] = 0.f;

        // ---- Phase A: write pf=(t,kc1)->se1; issue (t+1,kc0); compute se0 (k 0..31)
#pragma unroll
        for (int i = 0; i < 4; ++i) {
            se1[(pkb + 4 * i + 0) * 128 + prow] = pf[i].x;
            se1[(pkb + 4 * i + 1) * 128 + prow] = pf[i].y;
            se1[(pkb + 4 * i + 2) * 128 + prow] = pf[i].z;
            se1[(pkb + 4 * i + 3) * 128 + prow] = pf[i].w;
        }
        {
            const float* ep = keh + (size_t)(tn * CT + prow) * D + pkb;
#pragma unroll
            for (int i = 0; i < 4; ++i) pf[i] = ((const float4*)ep)[i];
        }
#pragma unroll 2
        for (int kk = 0; kk < 32; ++kk) {
            float4 xa0 = *(const float4*)&sx[kk * 128 + ty * 8];
            float4 xa1 = *(const float4*)&sx[kk * 128 + ty * 8 + 4];
            float4 e0  = *(const float4*)&se0[kk * 128 + tx * 4];
            float4 e1  = *(const float4*)&se0[kk * 128 + 64 + tx * 4];
            float xa[8] = {xa0.x, xa0.y, xa0.z, xa0.w, xa1.x, xa1.y, xa1.z, xa1.w};
            float eb[8] = {e0.x, e0.y, e0.z, e0.w, e1.x, e1.y, e1.z, e1.w};
#pragma unroll
            for (int r = 0; r < 8; ++r)
#pragma unroll
                for (int j = 0; j < 8; ++j)
                    acc[r][j] = fmaf(xa[r], eb[j], acc[r][j]);
        }
        __syncthreads();

        // ---- Phase B: write pf=(t+1,kc0)->se0; issue (t+1,kc1); compute se1 (k 32..63)
#pragma unroll
        for (int i = 0; i < 4; ++i) {
            se0[(pkb + 4 * i + 0) * 128 + prow] = pf[i].x;
            se0[(pkb + 4 * i + 1) * 128 + prow] = pf[i].y;
            se0[(pkb + 4 * i + 2) * 128 + prow] = pf[i].z;
            se0[(pkb + 4 * i + 3) * 128 + prow] = pf[i].w;
        }
        {
            const float* ep = keh + (size_t)(tn * CT + prow) * D + 32 + pkb;
#pragma unroll
            for (int i = 0; i < 4; ++i) pf[i] = ((const float4*)ep)[i];
        }
#pragma unroll 2
        for (int kk = 0; kk < 32; ++kk) {
            float4 xa0 = *(const float4*)&sx[(32 + kk) * 128 + ty * 8];
            float4 xa1 = *(const float4*)&sx[(32 + kk) * 128 + ty * 8 + 4];
            float4 e0  = *(const float4*)&se1[kk * 128 + tx * 4];
            float4 e1  = *(const float4*)&se1[kk * 128 + 64 + tx * 4];
            float xa[8] = {xa0.x, xa0.y, xa0.z, xa0.w, xa1.x, xa1.y, xa1.z, xa1.w};
            float eb[8] = {e0.x, e0.y, e0.z, e0.w, e1.x, e1.y, e1.z, e1.w};
#pragma unroll
            for (int r = 0; r < 8; ++r)
#pragma unroll
                for (int j = 0; j < 8; ++j)
                    acc[r][j] = fmaf(xa[r], eb[j], acc[r][j]);
        }

        // ---- epilogue tile t: score = esq[c] - 2*dot ; running first-min ----
        {
            float4 q0 = *(const float4*)&sesqa[t * CT + tx * 4];
            float4 q1 = *(const float4*)&sesqa[t * CT + 64 + tx * 4];
            float eq[8] = {q0.x, q0.y, q0.z, q0.w, q1.x, q1.y, q1.z, q1.w};
#pragma unroll
            for (int r = 0; r < 8; ++r) {
#pragma unroll
                for (int j = 0; j < 8; ++j) {   // ascending code order per thread
                    const int cc = (j < 4) ? (tx * 4 + j) : (64 + tx * 4 + (j - 4));
                    float sc = fmaf(-2.f, acc[r][j], eq[j]);
                    if (sc < best[r]) { best[r] = sc; bidx[r] = t * CT + cc; }
                }
            }
        }
        __syncthreads();
    }

    // ---- cross-thread argmin reduction (rb/ri alias se region) ----
    float* rb = smem + 8192;
    int*   ri = (int*)(smem + 10240);
#pragma unroll
    for (int r = 0; r < 8; ++r) {
        rb[tx * 128 + ty * 8 + r] = best[r];
        ri[tx * 128 + ty * 8 + r] = bidx[r];
    }
    __syncthreads();
    if (tid < 128) {
        const int v = tid;
        float bb = FLT_MAX;
        int   bi = 0x7fffffff;
        for (int g = 0; g < 16; ++g) {
            float b = rb[g * 128 + v];
            int   i = ri[g * 128 + v];
            if (b < bb || (b == bb && i < bi)) { bb = b; bi = i; }
        }
        sidx[v] = bi;
        outi[(size_t)(n0 + v) * H + h] = (float)bi;   // [b,t,h]
    }
    __syncthreads();

    // ---- gather quantized vectors + scatter-add into emb_sum ----
    {
        const int v  = tid >> 1;
        const int db = (tid & 1) * 32;
        const int ci = sidx[v];
        const float* ev = keh + (size_t)ci * D + db;
        float* qo = outq + (size_t)(n0 + v) * HD + (size_t)h * D + db;
#pragma unroll
        for (int i = 0; i < 8; ++i)
            ((float4*)qo)[i] = ((const float4*)ev)[i];

        float* es = embsum + ((size_t)h * C + ci) * D + db;
#pragma unroll
        for (int d = 0; d < 32; ++d)
            atomicAdd(es + d, sx[(db + d) * 128 + v]);
    }
}

// ---------------------------------------------------------------------------
// Kernel 2: new_ke = key_optim ? ke + 0.9*(emb_sum - ke) : ke
// ---------------------------------------------------------------------------
__global__ __launch_bounds__(256) void vq_lerp_kernel(const float* __restrict__ ke,
                                                      const float* __restrict__ embsum,
                                                      const int* __restrict__ ko,
                                                      float* __restrict__ outk) {
    int i = (blockIdx.x * 256 + threadIdx.x) * 4;   // H*C*D = 1048576 floats
    const int on = ko[0];
    float4 k4 = *(const float4*)(ke + i);
    float4 s4 = *(const float4*)(embsum + i);
    float4 o4;
    if (on) {
        o4.x = k4.x + DECAYF * (s4.x - k4.x);
        o4.y = k4.y + DECAYF * (s4.y - k4.y);
        o4.z = k4.z + DECAYF * (s4.z - k4.z);
        o4.w = k4.w + DECAYF * (s4.w - k4.w);
    } else {
        o4 = k4;
    }
    *(float4*)(outk + i) = o4;
}

extern "C" void kernel_launch(void* const* d_in, const int* in_sizes, int n_in,
                              void* d_out, int out_size, void* d_ws, size_t ws_size,
                              hipStream_t stream) {
    const float* x  = (const float*)d_in[0];
    const float* ke = (const float*)d_in[1];
    const int*   ko = (const int*)d_in[2];

    float* out  = (float*)d_out;
    float* outq = out;                                   // 8,388,608 floats
    float* outi = out + (size_t)H * NPH * D;             // +131,072 floats
    float* outk = outi + (size_t)NPH * H;                // +1,048,576 floats

    float* embsum = (float*)d_ws;                        // H*C*D f32
    float* esq    = embsum + (size_t)H * C * D;          // 16,384 f32

    // zero the scatter accumulator every call (graph-replay safe)
    hipMemsetAsync(embsum, 0, (size_t)H * C * D * sizeof(float), stream);

    vq_esq_kernel<<<(H * C) / 256, 256, 0, stream>>>(ke, esq);
    vq_main_kernel<<<1024, 256, 0, stream>>>(x, ke, esq, outq, outi, embsum);
    vq_lerp_kernel<<<(H * C * D) / (256 * 4), 256, 0, stream>>>(ke, embsum, ko, outk);
}